// Round 12
// baseline (366.651 us; speedup 1.0000x reference)
//
#include <hip/hip_runtime.h>

typedef __attribute__((ext_vector_type(8))) short short8;
typedef __attribute__((ext_vector_type(4))) float float4v;

#define NNODES 8192
#define SEQLEN 256
// h ping-pong row stride in shorts. 40 = 80B rows: ds_read_b128 at byte
// 80c+16q is 16B-aligned and its 16B-slot pattern (5c+q)&7 covers all 8
// slots evenly (8 lanes each) -> balanced. 42 regressed (misaligned b128).
#define HSTR 40

static __device__ __forceinline__ unsigned short f2bf(float f) {
  union { float f; unsigned u; } v; v.f = f;
  unsigned r = v.u + 0x7FFFu + ((v.u >> 16) & 1u);
  return (unsigned short)(r >> 16);
}
static __device__ __forceinline__ void splitbf8(const float* v, short8& hi) {
#pragma unroll
  for (int j = 0; j < 8; ++j) hi[j] = (short)f2bf(v[j]);
}
static __device__ __forceinline__ float asf(unsigned u) {
  union { unsigned u; float f; } v; v.u = u; return v.f;
}

// single cell (prologue only)
static __device__ __forceinline__ float lstm_cell(float zi, float zf, float zg,
                                                  float zo, float& c) {
  float ef = __builtin_amdgcn_exp2f(-zf);
  float ei = __builtin_amdgcn_exp2f(-zi);
  float eg = __builtin_amdgcn_exp2f(fminf(zg + zg, 60.f));
  float fterm = c * __builtin_amdgcn_rcpf(1.f + ef);
  float igt = (eg - 1.f) * __builtin_amdgcn_rcpf((1.f + ei) * (eg + 1.f));
  c = fterm + igt;
  float eo = __builtin_amdgcn_exp2f(-zo);
  float ec = __builtin_amdgcn_exp2f(fminf(2.88539008178f * c, 40.f));
  return (ec - 1.f) * __builtin_amdgcn_rcpf((1.f + eo) * (ec + 1.f));
}

// v21 SCALAR dual cell (10 exp2 + 3 rcp), independent chains until RQ.
// v23's float2v-packed version REGRESSED (259->311us): packed ops couple
// the two cells' dep chains (each v_pk awaits the later lane). Scalar.
static __device__ __forceinline__ void lstm_cell2(
    float z1i, float z1f, float z1g, float z1o,
    float z2i, float z2f, float z2g, float z2o,
    float& c1, float& c2, float& h1, float& h2) {
  float ef1 = __builtin_amdgcn_exp2f(-z1f);
  float ei1 = __builtin_amdgcn_exp2f(-z1i);
  float eg1 = __builtin_amdgcn_exp2f(fminf(z1g + z1g, 60.f));
  float A1 = 1.f + ef1;
  float D1 = (1.f + ei1) * (eg1 + 1.f);
  float R1 = __builtin_amdgcn_rcpf(A1 * D1);
  c1 = c1 * D1 * R1 + (eg1 - 1.f) * A1 * R1;

  float ef2 = __builtin_amdgcn_exp2f(-z2f);
  float ei2 = __builtin_amdgcn_exp2f(-z2i);
  float eg2 = __builtin_amdgcn_exp2f(fminf(z2g + z2g, 60.f));
  float A2 = 1.f + ef2;
  float D2 = (1.f + ei2) * (eg2 + 1.f);
  float R2 = __builtin_amdgcn_rcpf(A2 * D2);
  c2 = c2 * D2 * R2 + (eg2 - 1.f) * A2 * R2;

  float eo1 = __builtin_amdgcn_exp2f(-z1o);
  float ec1 = __builtin_amdgcn_exp2f(fminf(2.88539008178f * c1, 40.f));
  float eo2 = __builtin_amdgcn_exp2f(-z2o);
  float ec2 = __builtin_amdgcn_exp2f(fminf(2.88539008178f * c2, 40.f));
  float Q1 = (1.f + eo1) * (ec1 + 1.f);
  float Q2 = (1.f + eo2) * (ec2 + 1.f);
  float RQ = __builtin_amdgcn_rcpf(Q1 * Q2);
  h1 = (ec1 - 1.f) * Q2 * RQ;
  h2 = (ec2 - 1.f) * Q1 * RQ;
}

// v26 = v21 (verified 259us lstm / 356.6 total) + ONE latency fix:
// the s2 reduce's two __shfl_xor lower to index-calc + ds_bpermute
// (2 serial LDS round trips on the critical path). Replace with
// ds_swizzle 0x401F (xor16, one LDS op, no index math) +
// v_permlane32_swap (xor32 on the VALU; a+b = s2[i]+s2[i^32] in all
// lanes). Same add order as v21 -> bit-identical. [v25's dot2 reverted:
// VALUBusy 74->68 but time flat -> kernel is latency-bound now.]
__global__ __launch_bounds__(512, 4)
void lstm_fused(const float* __restrict__ x,
                const float* __restrict__ Wih1, const float* __restrict__ Whh1,
                const float* __restrict__ bih1, const float* __restrict__ bhh1,
                const float* __restrict__ ln_g, const float* __restrict__ ln_b,
                const float* __restrict__ Wih2, const float* __restrict__ Whh2,
                const float* __restrict__ bih2, const float* __restrict__ bhh2,
                const float* __restrict__ Wg1,
                const int* __restrict__ ei, const float* __restrict__ ew,
                unsigned long long* __restrict__ pkc, int E,
                float* __restrict__ h2out, float* __restrict__ hWa)
{
  const int tid = threadIdx.x;
  const int w = tid >> 6;
  const int lane = tid & 63;
  const int c = lane & 15;       // node index for this lane (output col)
  const int q = lane >> 4;       // k-group; hid = w*4 + q
  const int hid = w * 4 + q;
  const int nodeBase = blockIdx.x * 16;
  const float L = 1.44269504089f;

  __shared__ __align__(16) float xlds[16 * 260];
  __shared__ __align__(16) unsigned short h1p[2][16 * HSTR];
  __shared__ __align__(16) unsigned short h2p[2][16 * HSTR];
  __shared__ __align__(16) float wgbuf[32 * 33];
  __shared__ __align__(16) float h2f[16 * 33];

  for (int i = tid; i < 16 * 256; i += 512) {
    int nn = i >> 8, tt = i & 255;
    xlds[nn * 260 + tt] = x[(size_t)(nodeBase + nn) * SEQLEN + tt];
  }
  if (tid < 64) xlds[(tid >> 2) * 260 + 256 + (tid & 3)] = 0.f;
  for (int i = tid; i < 1024; i += 512) wgbuf[(i >> 5) * 33 + (i & 31)] = Wg1[i];

  // ---- folded count_k: one edge per thread (512 blk x 512 thr == E).
  for (int e = blockIdx.x * 512 + tid; e < E; e += gridDim.x * 512) {
    int d = ei[E + e];
    unsigned long long pay = (1ull << 40) |
        (unsigned long long)(unsigned)(ew[e] * 16777216.f + 0.5f);
    atomicAdd(&pkc[d], pay);
  }

  // Weight fragments (first mfma operand; lane (c,q) holds W[browF][q*8..+7]).
  const int browF = (c & 3) * 32 + w * 4 + (c >> 2);
  short8 Bh1, Bi2, Bh2;
  {
    float v[8];
#pragma unroll
    for (int j = 0; j < 8; ++j) v[j] = L * Whh1[browF * 32 + q * 8 + j];
    splitbf8(v, Bh1);
#pragma unroll
    for (int j = 0; j < 8; ++j) v[j] = L * Wih2[browF * 32 + q * 8 + j] * ln_g[q * 8 + j];
    splitbf8(v, Bi2);
#pragma unroll
    for (int j = 0; j < 8; ++j) v[j] = L * Whh2[browF * 32 + q * 8 + j];
    splitbf8(v, Bh2);
  }
  // all-ones A fragment: D = mfma(Ones, h1A, 0) -> D[r][c] = sum_k h[c][k]
  const short8 Ones = {0x3F80, 0x3F80, 0x3F80, 0x3F80,
                       0x3F80, 0x3F80, 0x3F80, 0x3F80};

  // Per-reg gate rows: reg r of this lane is gate row r*32 + hid.
  float Gp[4], C1a[4], C2a[4];
#pragma unroll
  for (int r = 0; r < 4; ++r) {
    const int br = r * 32 + hid;
    float sG = 0.f, sB = 0.f;
    for (int k = 0; k < 32; ++k) {
      float wv = Wih2[br * 32 + k];
      sG += wv * ln_g[k];
      sB += wv * ln_b[k];
    }
    Gp[r] = L * sG;
    C1a[r] = L * (bih1[br] + bhh1[br]);
    C2a[r] = L * (sB + bih2[br] + bhh2[br]);
  }
  const float4v C1 = {C1a[0], C1a[1], C1a[2], C1a[3]};
  const float4v C2 = {C2a[0], C2a[1], C2a[2], C2a[3]};
  const float4v z4 = {0.f, 0.f, 0.f, 0.f};
  float w1v[4];
#pragma unroll
  for (int g = 0; g < 4; ++g) w1v[g] = L * Wih1[g * 32 + hid];

  const int hWr = c * HSTR + hid;     // this lane's (node, hid) h-slot
  const int hRd = c * HSTR + q * 8;   // next-iter fragment read

  short8 h1A = {0,0,0,0,0,0,0,0};
  short8 h2A = {0,0,0,0,0,0,0,0};
  float c1 = 0.f, c2 = 0.f, hv2 = 0.f;
  __syncthreads();

  // ---- prologue: h=0 -> z = bias; consume x[0] -> h1(0) in h1p[1] ----
  {
    float xv = xlds[c * 260 + 0];
    float hv = lstm_cell(fmaf(xv, w1v[0], C1[0]), fmaf(xv, w1v[1], C1[1]),
                         fmaf(xv, w1v[2], C1[2]), fmaf(xv, w1v[3], C1[3]), c1);
    h1p[1][hWr] = f2bf(hv);
  }
  __syncthreads();
  h1A = *(const short8*)&h1p[1][hRd];

  auto step = [&](int t, int pl) {
    // x-contribution folded into MFMA C-in (x resident in LDS since start)
    float xv = xlds[c * 260 + t + 1];
    float4v Cx = {fmaf(xv, w1v[0], C1[0]), fmaf(xv, w1v[1], C1[1]),
                  fmaf(xv, w1v[2], C1[2]), fmaf(xv, w1v[3], C1[3])};
    // swapped operands: D[row=gate r, hid][col=node c]
    float4v za = __builtin_amdgcn_mfma_f32_16x16x32_bf16(Bh1, h1A, Cx, 0, 0, 0);
    float4v db = __builtin_amdgcn_mfma_f32_16x16x32_bf16(Bh2, h2A, C2, 0, 0, 0);
    float4v sv = __builtin_amdgcn_mfma_f32_16x16x32_bf16(Ones, h1A, z4, 0, 0, 0);

    // LN: s free from sv (any reg); s2 via packed unpack + fma
    float s2 = 0.f;
    {
      const unsigned* hw = (const unsigned*)&h1A;
#pragma unroll
      for (int j = 0; j < 4; ++j) {
        unsigned u = hw[j];
        float flo = asf(u << 16);
        float fhi = asf(u & 0xFFFF0000u);
        s2 = fmaf(flo, flo, s2);
        s2 = fmaf(fhi, fhi, s2);
      }
    }
    // xor16: single ds_swizzle (BitMode xor=0x10,and=0x1F -> 0x401F)
    s2 += asf((unsigned)__builtin_amdgcn_ds_swizzle(
                  (int)__float_as_uint(s2), 0x401F));
    // xor32: v_permlane32_swap on the VALU (no LDS round trip).
    // After swap: a+b = s2[i] + s2[i^32] in every lane (same add order).
    {
      float a = s2, b = s2;
      asm("v_permlane32_swap_b32 %0, %1" : "+v"(a), "+v"(b));
      s2 = a + b;
    }
    float mu = sv[0] * (1.f / 32.f);
    float var = fmaf(s2, 1.f / 32.f, -mu * mu);
    float rstd = __builtin_amdgcn_rsqf(var + 1e-5f);
    float mur = rstd * mu;

    float4v da = __builtin_amdgcn_mfma_f32_16x16x32_bf16(Bi2, h1A, z4, 0, 0, 0);

    // cell2: z2[r] = rstd*da[r] - mur*Gp[r] + db[r]; dual-cell evaluate
    float hv, hvb;
    lstm_cell2(za[0], za[1], za[2], za[3],
               fmaf(rstd, da[0], fmaf(-mur, Gp[0], db[0])),
               fmaf(rstd, da[1], fmaf(-mur, Gp[1], db[1])),
               fmaf(rstd, da[2], fmaf(-mur, Gp[2], db[2])),
               fmaf(rstd, da[3], fmaf(-mur, Gp[3], db[3])),
               c1, c2, hv, hvb);
    hv2 = hvb;

    // pack both h values with one v_cvt_pk_bf16_f32 (RNE, matches f2bf)
    unsigned pk;
    asm("v_cvt_pk_bf16_f32 %0, %1, %2" : "=v"(pk) : "v"(hv), "v"(hv2));
    h1p[pl][hWr] = (unsigned short)pk;          // ds_write_b16 (lo)
    h2p[pl][hWr] = (unsigned short)(pk >> 16);  // ds_write_b16_d16_hi

    __syncthreads();
    h1A = *(const short8*)&h1p[pl][hRd];
    h2A = *(const short8*)&h2p[pl][hRd];
  };

  for (int t = 0; t < SEQLEN; t += 2) {
    step(t, 0);       // pl compile-time 0
    step(t + 1, 1);   // pl compile-time 1
  }

  h2out[(size_t)(nodeBase + c) * 32 + hid] = hv2;

  h2f[c * 33 + hid] = hv2;
  __syncthreads();
  {
    int nl = tid >> 5, j = tid & 31;
    float acc = 0.f;
#pragma unroll
    for (int k = 0; k < 32; ++k) acc = fmaf(h2f[nl * 33 + k], wgbuf[k * 33 + j], acc);
    hWa[(size_t)(nodeBase + nl) * 32 + j] = acc;
  }
}

// ---------------- GCN ----------------
// wave-shuffle hierarchical scan: 2 barriers
__global__ __launch_bounds__(1024, 1)
void scan_k(const unsigned long long* __restrict__ pk, int* __restrict__ off,
            int* __restrict__ pos, float* __restrict__ dinv) {
  __shared__ int wtot[16];
  __shared__ int wexcl[16];
  int tid = threadIdx.x;
  int wv = tid >> 6, lane = tid & 63;
  int base = tid * 8;
  int v[8]; int sum = 0;
#pragma unroll
  for (int i = 0; i < 8; ++i) {
    unsigned long long u = pk[base + i];
    v[i] = (int)(u >> 40);
    float degv = (float)(u & 0xFFFFFFFFFFull) * (1.f / 16777216.f);
    dinv[base + i] = rsqrtf(degv + 1.0f);
    sum += v[i];
  }
  int incl = sum;
#pragma unroll
  for (int d = 1; d < 64; d <<= 1) {
    int t = __shfl_up(incl, d, 64);
    if (lane >= d) incl += t;
  }
  if (lane == 63) wtot[wv] = incl;
  __syncthreads();
  if (wv == 0 && lane < 16) {
    int wval = wtot[lane];
    int wincl = wval;
#pragma unroll
    for (int d = 1; d < 16; d <<= 1) {
      int t = __shfl_up(wincl, d, 64);
      if (lane >= d) wincl += t;
    }
    wexcl[lane] = wincl - wval;
  }
  __syncthreads();
  int run = wexcl[wv] + (incl - sum);
#pragma unroll
  for (int i = 0; i < 8; ++i) {
    off[base + i] = run; pos[base + i] = run; run += v[i];
  }
  if (tid == 1023) off[8192] = run;
}

__global__ void scatter_k(const int* __restrict__ ei, const float* __restrict__ ew,
                          const float* __restrict__ dinv, int* __restrict__ pos,
                          int2* __restrict__ ed, int E) {
  int e = blockIdx.x * 256 + threadIdx.x;
  if (e >= E) return;
  int sidx = ei[e], d = ei[E + e];
  int p = atomicAdd(&pos[d], 1);
  int2 pay;
  pay.x = sidx;
  pay.y = __float_as_int(dinv[sidx] * ew[e] * dinv[d]);
  ed[p] = pay;
}

// conv1 gather (unroll-4) + elu + (g1 @ Wg2); 16 nodes/block
__global__ __launch_bounds__(512, 4)
void gather_mid_k(const int* __restrict__ off, const int2* __restrict__ ed,
                  const float* __restrict__ dinv, const float* __restrict__ hWa,
                  const float* __restrict__ bg1, const float* __restrict__ Wg2,
                  float* __restrict__ aggB) {
  __shared__ float wg[32 * 33];
  __shared__ float g1buf[16][33];
  int tid = threadIdx.x;
  for (int i = tid; i < 1024; i += 512) wg[(i >> 5) * 33 + (i & 31)] = Wg2[i];
  int nl = tid >> 5, j = tid & 31;
  int node = blockIdx.x * 16 + nl;
  float dv = dinv[node];
  float a0 = dv * dv * hWa[(size_t)node * 32 + j];
  float a1 = 0.f, a2 = 0.f, a3 = 0.f;
  int p0 = off[node], p1 = off[node + 1];
  int p = p0;
  for (; p + 3 < p1; p += 4) {
    int2 e0 = ed[p], e1 = ed[p + 1], e2 = ed[p + 2], e3 = ed[p + 3];
    a0 = fmaf(__int_as_float(e0.y), hWa[(size_t)e0.x * 32 + j], a0);
    a1 = fmaf(__int_as_float(e1.y), hWa[(size_t)e1.x * 32 + j], a1);
    a2 = fmaf(__int_as_float(e2.y), hWa[(size_t)e2.x * 32 + j], a2);
    a3 = fmaf(__int_as_float(e3.y), hWa[(size_t)e3.x * 32 + j], a3);
  }
  for (; p < p1; ++p) {
    int2 e0 = ed[p];
    a0 = fmaf(__int_as_float(e0.y), hWa[(size_t)e0.x * 32 + j], a0);
  }
  float v = (a0 + a1) + (a2 + a3) + bg1[j];
  g1buf[nl][j] = (v > 0.f) ? v : expm1f(v);
  __syncthreads();
  float acc = 0.f;
#pragma unroll
  for (int k = 0; k < 32; ++k) acc = fmaf(g1buf[nl][k], wg[k * 33 + j], acc);
  aggB[(size_t)node * 32 + j] = acc;
}

// conv2 gather (unroll-4) + elu + mean + fc + log-softmax; 16 nodes/block
__global__ __launch_bounds__(512, 4)
void gather_final_k(const int* __restrict__ off, const int2* __restrict__ ed,
                    const float* __restrict__ dinv, const float* __restrict__ aggB,
                    const float* __restrict__ bg2, const float* __restrict__ h2o,
                    const float* __restrict__ Wfc, const float* __restrict__ bfc,
                    float* __restrict__ out) {
  int tid = threadIdx.x;
  int nl = tid >> 5, j = tid & 31;
  int node = blockIdx.x * 16 + nl;
  float dv = dinv[node];
  float a0 = dv * dv * aggB[(size_t)node * 32 + j];
  float a1 = 0.f, a2 = 0.f, a3 = 0.f;
  int p0 = off[node], p1 = off[node + 1];
  int p = p0;
  for (; p + 3 < p1; p += 4) {
    int2 e0 = ed[p], e1 = ed[p + 1], e2 = ed[p + 2], e3 = ed[p + 3];
    a0 = fmaf(__int_as_float(e0.y), aggB[(size_t)e0.x * 32 + j], a0);
    a1 = fmaf(__int_as_float(e1.y), aggB[(size_t)e1.x * 32 + j], a1);
    a2 = fmaf(__int_as_float(e2.y), aggB[(size_t)e2.x * 32 + j], a2);
    a3 = fmaf(__int_as_float(e3.y), aggB[(size_t)e3.x * 32 + j], a3);
  }
  for (; p < p1; ++p) {
    int2 e0 = ed[p];
    a0 = fmaf(__int_as_float(e0.y), aggB[(size_t)e0.x * 32 + j], a0);
  }
  float v = (a0 + a1) + (a2 + a3) + bg2[j];
  float e = (v > 0.f) ? v : expm1f(v);
  float h2v = h2o[(size_t)node * 32 + j];
  float p0s = h2v * Wfc[j];
  float p1s = h2v * Wfc[33 + j];
#pragma unroll
  for (int m = 1; m < 32; m <<= 1) {
    e   += __shfl_xor(e, m, 32);
    p0s += __shfl_xor(p0s, m, 32);
    p1s += __shfl_xor(p1s, m, 32);
  }
  if (j == 0) {
    float mean = e * (1.f / 32.f);
    float o0 = p0s + mean * Wfc[32] + bfc[0];
    float o1 = p1s + mean * Wfc[65] + bfc[1];
    float mx = fmaxf(o0, o1);
    float l = mx + logf(expf(o0 - mx) + expf(o1 - mx));
    out[node * 2 + 0] = o0 - l;
    out[node * 2 + 1] = o1 - l;
  }
}

extern "C" void kernel_launch(void* const* d_in, const int* in_sizes, int n_in,
                              void* d_out, int out_size, void* d_ws, size_t ws_size,
                              hipStream_t stream) {
  const float* x    = (const float*)d_in[0];
  const float* ew   = (const float*)d_in[1];
  const float* Wih1 = (const float*)d_in[2];
  const float* Whh1 = (const float*)d_in[3];
  const float* bih1 = (const float*)d_in[4];
  const float* bhh1 = (const float*)d_in[5];
  const float* ln_g = (const float*)d_in[6];
  const float* ln_b = (const float*)d_in[7];
  const float* Wih2 = (const float*)d_in[8];
  const float* Whh2 = (const float*)d_in[9];
  const float* bih2 = (const float*)d_in[10];
  const float* bhh2 = (const float*)d_in[11];
  const float* Wg1  = (const float*)d_in[12];
  const float* bg1  = (const float*)d_in[13];
  const float* Wg2  = (const float*)d_in[14];
  const float* bg2  = (const float*)d_in[15];
  const float* Wfc  = (const float*)d_in[16];
  const float* bfc  = (const float*)d_in[17];
  const int* ei     = (const int*)d_in[18];
  float* out = (float*)d_out;
  const int E = in_sizes[1];   // 262144

  float* ws   = (float*)d_ws;
  float* h2o  = ws;                    // 262144
  float* hWa  = ws + 262144;           // 262144
  float* aggB = ws + 524288;           // 262144
  unsigned long long* pk = (unsigned long long*)(ws + 786432);  // 8192 ull
  float* dinv = ws + 802816;           // 8192
  int*   off  = (int*)(ws + 811008);   // 8193
  int*   pos  = (int*)(ws + 819208);   // 8192
  int2*  ed   = (int2*)(ws + 827400);  // 262144 int2

  hipMemsetAsync((void*)pk, 0, 8192 * sizeof(unsigned long long), stream);
  hipLaunchKernelGGL(lstm_fused, dim3(NNODES / 16), dim3(512), 0, stream,
                     x, Wih1, Whh1, bih1, bhh1, ln_g, ln_b,
                     Wih2, Whh2, bih2, bhh2, Wg1, ei, ew, pk, E, h2o, hWa);
  hipLaunchKernelGGL(scan_k, dim3(1), dim3(1024), 0, stream, pk, off, pos, dinv);
  hipLaunchKernelGGL(scatter_k, dim3((E + 255) / 256), dim3(256), 0, stream, ei, ew, dinv, pos, ed, E);
  hipLaunchKernelGGL(gather_mid_k, dim3(NNODES / 16), dim3(512), 0, stream,
                     off, ed, dinv, hWa, bg1, Wg2, aggB);
  hipLaunchKernelGGL(gather_final_k, dim3(NNODES / 16), dim3(512), 0, stream,
                     off, ed, dinv, aggB, bg2, h2o, Wfc, bfc, out);
}

// Round 13
// 355.182 us; speedup vs baseline: 1.0323x; 1.0323x over previous
//
#include <hip/hip_runtime.h>

typedef __attribute__((ext_vector_type(8))) short short8;
typedef __attribute__((ext_vector_type(4))) float float4v;

#define NNODES 8192
#define SEQLEN 256
// h ping-pong row stride in shorts. 40 = 80B rows: ds_read_b128 at byte
// 80c+16q is 16B-aligned and its 16B-slot pattern (5c+q)&7 covers all 8
// slots evenly (8 lanes each) -> balanced. 42 regressed (misaligned b128).
#define HSTR 40

static __device__ __forceinline__ unsigned short f2bf(float f) {
  union { float f; unsigned u; } v; v.f = f;
  unsigned r = v.u + 0x7FFFu + ((v.u >> 16) & 1u);
  return (unsigned short)(r >> 16);
}
static __device__ __forceinline__ void splitbf8(const float* v, short8& hi) {
#pragma unroll
  for (int j = 0; j < 8; ++j) hi[j] = (short)f2bf(v[j]);
}
static __device__ __forceinline__ float asf(unsigned u) {
  union { unsigned u; float f; } v; v.u = u; return v.f;
}

// single cell (prologue only)
static __device__ __forceinline__ float lstm_cell(float zi, float zf, float zg,
                                                  float zo, float& c) {
  float ef = __builtin_amdgcn_exp2f(-zf);
  float ei = __builtin_amdgcn_exp2f(-zi);
  float eg = __builtin_amdgcn_exp2f(fminf(zg + zg, 60.f));
  float fterm = c * __builtin_amdgcn_rcpf(1.f + ef);
  float igt = (eg - 1.f) * __builtin_amdgcn_rcpf((1.f + ei) * (eg + 1.f));
  c = fterm + igt;
  float eo = __builtin_amdgcn_exp2f(-zo);
  float ec = __builtin_amdgcn_exp2f(fminf(2.88539008178f * c, 40.f));
  return (ec - 1.f) * __builtin_amdgcn_rcpf((1.f + eo) * (ec + 1.f));
}

// v21 SCALAR dual cell, rcp-merged: 10 exp2 + 3 rcp. Chains stay
// independent until RQ -> scheduler interleaves them to hide trans
// latency. (v23's float2v packing coupled the chains: 259->311us.)
static __device__ __forceinline__ void lstm_cell2(
    float z1i, float z1f, float z1g, float z1o,
    float z2i, float z2f, float z2g, float z2o,
    float& c1, float& c2, float& h1, float& h2) {
  float ef1 = __builtin_amdgcn_exp2f(-z1f);
  float ei1 = __builtin_amdgcn_exp2f(-z1i);
  float eg1 = __builtin_amdgcn_exp2f(fminf(z1g + z1g, 60.f));
  float A1 = 1.f + ef1;
  float D1 = (1.f + ei1) * (eg1 + 1.f);
  float R1 = __builtin_amdgcn_rcpf(A1 * D1);
  c1 = c1 * D1 * R1 + (eg1 - 1.f) * A1 * R1;

  float ef2 = __builtin_amdgcn_exp2f(-z2f);
  float ei2 = __builtin_amdgcn_exp2f(-z2i);
  float eg2 = __builtin_amdgcn_exp2f(fminf(z2g + z2g, 60.f));
  float A2 = 1.f + ef2;
  float D2 = (1.f + ei2) * (eg2 + 1.f);
  float R2 = __builtin_amdgcn_rcpf(A2 * D2);
  c2 = c2 * D2 * R2 + (eg2 - 1.f) * A2 * R2;

  float eo1 = __builtin_amdgcn_exp2f(-z1o);
  float ec1 = __builtin_amdgcn_exp2f(fminf(2.88539008178f * c1, 40.f));
  float eo2 = __builtin_amdgcn_exp2f(-z2o);
  float ec2 = __builtin_amdgcn_exp2f(fminf(2.88539008178f * c2, 40.f));
  float Q1 = (1.f + eo1) * (ec1 + 1.f);
  float Q2 = (1.f + eo2) * (ec2 + 1.f);
  float RQ = __builtin_amdgcn_rcpf(Q1 * Q2);
  h1 = (ec1 - 1.f) * Q2 * RQ;
  h2 = (ec2 - 1.f) * Q1 * RQ;
}

// v27 == v21 EXACT (best verified: lstm 259us / total 356.6us at R7).
// Plateau confirmed by 5 failed probes (v22-v26: packed math -20%,
// tail overlap -12%, dot2 flat, swizzle/permlane flat). Structural
// arithmetic: 455 issue-cyc/wave-iter (224 = minimal 14 trans ops)
// x 4 waves/SIMD = 1820 cyc floor vs 2430 measured; the 25% gap is
// barrier convoy, not removable at HIP source level.
__global__ __launch_bounds__(512, 4)
void lstm_fused(const float* __restrict__ x,
                const float* __restrict__ Wih1, const float* __restrict__ Whh1,
                const float* __restrict__ bih1, const float* __restrict__ bhh1,
                const float* __restrict__ ln_g, const float* __restrict__ ln_b,
                const float* __restrict__ Wih2, const float* __restrict__ Whh2,
                const float* __restrict__ bih2, const float* __restrict__ bhh2,
                const float* __restrict__ Wg1,
                const int* __restrict__ ei, const float* __restrict__ ew,
                unsigned long long* __restrict__ pkc, int E,
                float* __restrict__ h2out, float* __restrict__ hWa)
{
  const int tid = threadIdx.x;
  const int w = tid >> 6;
  const int lane = tid & 63;
  const int c = lane & 15;       // node index for this lane (output col)
  const int q = lane >> 4;       // k-group; hid = w*4 + q
  const int hid = w * 4 + q;
  const int nodeBase = blockIdx.x * 16;
  const float L = 1.44269504089f;

  __shared__ __align__(16) float xlds[16 * 260];
  __shared__ __align__(16) unsigned short h1p[2][16 * HSTR];
  __shared__ __align__(16) unsigned short h2p[2][16 * HSTR];
  __shared__ __align__(16) float wgbuf[32 * 33];
  __shared__ __align__(16) float h2f[16 * 33];

  for (int i = tid; i < 16 * 256; i += 512) {
    int nn = i >> 8, tt = i & 255;
    xlds[nn * 260 + tt] = x[(size_t)(nodeBase + nn) * SEQLEN + tt];
  }
  if (tid < 64) xlds[(tid >> 2) * 260 + 256 + (tid & 3)] = 0.f;
  for (int i = tid; i < 1024; i += 512) wgbuf[(i >> 5) * 33 + (i & 31)] = Wg1[i];

  // ---- folded count_k: one edge per thread (512 blk x 512 thr == E).
  for (int e = blockIdx.x * 512 + tid; e < E; e += gridDim.x * 512) {
    int d = ei[E + e];
    unsigned long long pay = (1ull << 40) |
        (unsigned long long)(unsigned)(ew[e] * 16777216.f + 0.5f);
    atomicAdd(&pkc[d], pay);
  }

  // Weight fragments (first mfma operand; lane (c,q) holds W[browF][q*8..+7]).
  const int browF = (c & 3) * 32 + w * 4 + (c >> 2);
  short8 Bh1, Bi2, Bh2;
  {
    float v[8];
#pragma unroll
    for (int j = 0; j < 8; ++j) v[j] = L * Whh1[browF * 32 + q * 8 + j];
    splitbf8(v, Bh1);
#pragma unroll
    for (int j = 0; j < 8; ++j) v[j] = L * Wih2[browF * 32 + q * 8 + j] * ln_g[q * 8 + j];
    splitbf8(v, Bi2);
#pragma unroll
    for (int j = 0; j < 8; ++j) v[j] = L * Whh2[browF * 32 + q * 8 + j];
    splitbf8(v, Bh2);
  }
  // all-ones A fragment: D = mfma(Ones, h1A, 0) -> D[r][c] = sum_k h[c][k]
  const short8 Ones = {0x3F80, 0x3F80, 0x3F80, 0x3F80,
                       0x3F80, 0x3F80, 0x3F80, 0x3F80};

  // Per-reg gate rows: reg r of this lane is gate row r*32 + hid.
  float Gp[4], C1a[4], C2a[4];
#pragma unroll
  for (int r = 0; r < 4; ++r) {
    const int br = r * 32 + hid;
    float sG = 0.f, sB = 0.f;
    for (int k = 0; k < 32; ++k) {
      float wv = Wih2[br * 32 + k];
      sG += wv * ln_g[k];
      sB += wv * ln_b[k];
    }
    Gp[r] = L * sG;
    C1a[r] = L * (bih1[br] + bhh1[br]);
    C2a[r] = L * (sB + bih2[br] + bhh2[br]);
  }
  const float4v C1 = {C1a[0], C1a[1], C1a[2], C1a[3]};
  const float4v C2 = {C2a[0], C2a[1], C2a[2], C2a[3]};
  const float4v z4 = {0.f, 0.f, 0.f, 0.f};
  float w1v[4];
#pragma unroll
  for (int g = 0; g < 4; ++g) w1v[g] = L * Wih1[g * 32 + hid];

  const int hWr = c * HSTR + hid;     // this lane's (node, hid) h-slot
  const int hRd = c * HSTR + q * 8;   // next-iter fragment read

  short8 h1A = {0,0,0,0,0,0,0,0};
  short8 h2A = {0,0,0,0,0,0,0,0};
  float c1 = 0.f, c2 = 0.f, hv2 = 0.f;
  __syncthreads();

  // ---- prologue: h=0 -> z = bias; consume x[0] -> h1(0) in h1p[1] ----
  {
    float xv = xlds[c * 260 + 0];
    float hv = lstm_cell(fmaf(xv, w1v[0], C1[0]), fmaf(xv, w1v[1], C1[1]),
                         fmaf(xv, w1v[2], C1[2]), fmaf(xv, w1v[3], C1[3]), c1);
    h1p[1][hWr] = f2bf(hv);
  }
  __syncthreads();
  h1A = *(const short8*)&h1p[1][hRd];

  auto step = [&](int t, int pl) {
    // x-contribution folded into MFMA C-in (x resident in LDS since start)
    float xv = xlds[c * 260 + t + 1];
    float4v Cx = {fmaf(xv, w1v[0], C1[0]), fmaf(xv, w1v[1], C1[1]),
                  fmaf(xv, w1v[2], C1[2]), fmaf(xv, w1v[3], C1[3])};
    // swapped operands: D[row=gate r, hid][col=node c]
    float4v za = __builtin_amdgcn_mfma_f32_16x16x32_bf16(Bh1, h1A, Cx, 0, 0, 0);
    float4v db = __builtin_amdgcn_mfma_f32_16x16x32_bf16(Bh2, h2A, C2, 0, 0, 0);
    float4v sv = __builtin_amdgcn_mfma_f32_16x16x32_bf16(Ones, h1A, z4, 0, 0, 0);

    // LN: s free from sv (any reg); s2 via packed unpack + fma
    float s2 = 0.f;
    {
      const unsigned* hw = (const unsigned*)&h1A;
#pragma unroll
      for (int j = 0; j < 4; ++j) {
        unsigned u = hw[j];
        float flo = asf(u << 16);
        float fhi = asf(u & 0xFFFF0000u);
        s2 = fmaf(flo, flo, s2);
        s2 = fmaf(fhi, fhi, s2);
      }
    }
    s2 += __shfl_xor(s2, 16, 64); s2 += __shfl_xor(s2, 32, 64);
    float mu = sv[0] * (1.f / 32.f);
    float var = fmaf(s2, 1.f / 32.f, -mu * mu);
    float rstd = __builtin_amdgcn_rsqf(var + 1e-5f);
    float mur = rstd * mu;

    float4v da = __builtin_amdgcn_mfma_f32_16x16x32_bf16(Bi2, h1A, z4, 0, 0, 0);

    // cell2: z2[r] = rstd*da[r] - mur*Gp[r] + db[r]; dual-cell evaluate
    float hv, hvb;
    lstm_cell2(za[0], za[1], za[2], za[3],
               fmaf(rstd, da[0], fmaf(-mur, Gp[0], db[0])),
               fmaf(rstd, da[1], fmaf(-mur, Gp[1], db[1])),
               fmaf(rstd, da[2], fmaf(-mur, Gp[2], db[2])),
               fmaf(rstd, da[3], fmaf(-mur, Gp[3], db[3])),
               c1, c2, hv, hvb);
    hv2 = hvb;

    // pack both h values with one v_cvt_pk_bf16_f32 (RNE, matches f2bf)
    unsigned pk;
    asm("v_cvt_pk_bf16_f32 %0, %1, %2" : "=v"(pk) : "v"(hv), "v"(hv2));
    h1p[pl][hWr] = (unsigned short)pk;          // ds_write_b16 (lo)
    h2p[pl][hWr] = (unsigned short)(pk >> 16);  // ds_write_b16_d16_hi

    __syncthreads();
    h1A = *(const short8*)&h1p[pl][hRd];
    h2A = *(const short8*)&h2p[pl][hRd];
  };

  for (int t = 0; t < SEQLEN; t += 2) {
    step(t, 0);       // pl compile-time 0
    step(t + 1, 1);   // pl compile-time 1
  }

  h2out[(size_t)(nodeBase + c) * 32 + hid] = hv2;

  h2f[c * 33 + hid] = hv2;
  __syncthreads();
  {
    int nl = tid >> 5, j = tid & 31;
    float acc = 0.f;
#pragma unroll
    for (int k = 0; k < 32; ++k) acc = fmaf(h2f[nl * 33 + k], wgbuf[k * 33 + j], acc);
    hWa[(size_t)(nodeBase + nl) * 32 + j] = acc;
  }
}

// ---------------- GCN ----------------
// wave-shuffle hierarchical scan: 2 barriers
__global__ __launch_bounds__(1024, 1)
void scan_k(const unsigned long long* __restrict__ pk, int* __restrict__ off,
            int* __restrict__ pos, float* __restrict__ dinv) {
  __shared__ int wtot[16];
  __shared__ int wexcl[16];
  int tid = threadIdx.x;
  int wv = tid >> 6, lane = tid & 63;
  int base = tid * 8;
  int v[8]; int sum = 0;
#pragma unroll
  for (int i = 0; i < 8; ++i) {
    unsigned long long u = pk[base + i];
    v[i] = (int)(u >> 40);
    float degv = (float)(u & 0xFFFFFFFFFFull) * (1.f / 16777216.f);
    dinv[base + i] = rsqrtf(degv + 1.0f);
    sum += v[i];
  }
  int incl = sum;
#pragma unroll
  for (int d = 1; d < 64; d <<= 1) {
    int t = __shfl_up(incl, d, 64);
    if (lane >= d) incl += t;
  }
  if (lane == 63) wtot[wv] = incl;
  __syncthreads();
  if (wv == 0 && lane < 16) {
    int wval = wtot[lane];
    int wincl = wval;
#pragma unroll
    for (int d = 1; d < 16; d <<= 1) {
      int t = __shfl_up(wincl, d, 64);
      if (lane >= d) wincl += t;
    }
    wexcl[lane] = wincl - wval;
  }
  __syncthreads();
  int run = wexcl[wv] + (incl - sum);
#pragma unroll
  for (int i = 0; i < 8; ++i) {
    off[base + i] = run; pos[base + i] = run; run += v[i];
  }
  if (tid == 1023) off[8192] = run;
}

__global__ void scatter_k(const int* __restrict__ ei, const float* __restrict__ ew,
                          const float* __restrict__ dinv, int* __restrict__ pos,
                          int2* __restrict__ ed, int E) {
  int e = blockIdx.x * 256 + threadIdx.x;
  if (e >= E) return;
  int sidx = ei[e], d = ei[E + e];
  int p = atomicAdd(&pos[d], 1);
  int2 pay;
  pay.x = sidx;
  pay.y = __float_as_int(dinv[sidx] * ew[e] * dinv[d]);
  ed[p] = pay;
}

// conv1 gather (unroll-4) + elu + (g1 @ Wg2); 16 nodes/block
__global__ __launch_bounds__(512, 4)
void gather_mid_k(const int* __restrict__ off, const int2* __restrict__ ed,
                  const float* __restrict__ dinv, const float* __restrict__ hWa,
                  const float* __restrict__ bg1, const float* __restrict__ Wg2,
                  float* __restrict__ aggB) {
  __shared__ float wg[32 * 33];
  __shared__ float g1buf[16][33];
  int tid = threadIdx.x;
  for (int i = tid; i < 1024; i += 512) wg[(i >> 5) * 33 + (i & 31)] = Wg2[i];
  int nl = tid >> 5, j = tid & 31;
  int node = blockIdx.x * 16 + nl;
  float dv = dinv[node];
  float a0 = dv * dv * hWa[(size_t)node * 32 + j];
  float a1 = 0.f, a2 = 0.f, a3 = 0.f;
  int p0 = off[node], p1 = off[node + 1];
  int p = p0;
  for (; p + 3 < p1; p += 4) {
    int2 e0 = ed[p], e1 = ed[p + 1], e2 = ed[p + 2], e3 = ed[p + 3];
    a0 = fmaf(__int_as_float(e0.y), hWa[(size_t)e0.x * 32 + j], a0);
    a1 = fmaf(__int_as_float(e1.y), hWa[(size_t)e1.x * 32 + j], a1);
    a2 = fmaf(__int_as_float(e2.y), hWa[(size_t)e2.x * 32 + j], a2);
    a3 = fmaf(__int_as_float(e3.y), hWa[(size_t)e3.x * 32 + j], a3);
  }
  for (; p < p1; ++p) {
    int2 e0 = ed[p];
    a0 = fmaf(__int_as_float(e0.y), hWa[(size_t)e0.x * 32 + j], a0);
  }
  float v = (a0 + a1) + (a2 + a3) + bg1[j];
  g1buf[nl][j] = (v > 0.f) ? v : expm1f(v);
  __syncthreads();
  float acc = 0.f;
#pragma unroll
  for (int k = 0; k < 32; ++k) acc = fmaf(g1buf[nl][k], wg[k * 33 + j], acc);
  aggB[(size_t)node * 32 + j] = acc;
}

// conv2 gather (unroll-4) + elu + mean + fc + log-softmax; 16 nodes/block
__global__ __launch_bounds__(512, 4)
void gather_final_k(const int* __restrict__ off, const int2* __restrict__ ed,
                    const float* __restrict__ dinv, const float* __restrict__ aggB,
                    const float* __restrict__ bg2, const float* __restrict__ h2o,
                    const float* __restrict__ Wfc, const float* __restrict__ bfc,
                    float* __restrict__ out) {
  int tid = threadIdx.x;
  int nl = tid >> 5, j = tid & 31;
  int node = blockIdx.x * 16 + nl;
  float dv = dinv[node];
  float a0 = dv * dv * aggB[(size_t)node * 32 + j];
  float a1 = 0.f, a2 = 0.f, a3 = 0.f;
  int p0 = off[node], p1 = off[node + 1];
  int p = p0;
  for (; p + 3 < p1; p += 4) {
    int2 e0 = ed[p], e1 = ed[p + 1], e2 = ed[p + 2], e3 = ed[p + 3];
    a0 = fmaf(__int_as_float(e0.y), aggB[(size_t)e0.x * 32 + j], a0);
    a1 = fmaf(__int_as_float(e1.y), aggB[(size_t)e1.x * 32 + j], a1);
    a2 = fmaf(__int_as_float(e2.y), aggB[(size_t)e2.x * 32 + j], a2);
    a3 = fmaf(__int_as_float(e3.y), aggB[(size_t)e3.x * 32 + j], a3);
  }
  for (; p < p1; ++p) {
    int2 e0 = ed[p];
    a0 = fmaf(__int_as_float(e0.y), aggB[(size_t)e0.x * 32 + j], a0);
  }
  float v = (a0 + a1) + (a2 + a3) + bg2[j];
  float e = (v > 0.f) ? v : expm1f(v);
  float h2v = h2o[(size_t)node * 32 + j];
  float p0s = h2v * Wfc[j];
  float p1s = h2v * Wfc[33 + j];
#pragma unroll
  for (int m = 1; m < 32; m <<= 1) {
    e   += __shfl_xor(e, m, 32);
    p0s += __shfl_xor(p0s, m, 32);
    p1s += __shfl_xor(p1s, m, 32);
  }
  if (j == 0) {
    float mean = e * (1.f / 32.f);
    float o0 = p0s + mean * Wfc[32] + bfc[0];
    float o1 = p1s + mean * Wfc[65] + bfc[1];
    float mx = fmaxf(o0, o1);
    float l = mx + logf(expf(o0 - mx) + expf(o1 - mx));
    out[node * 2 + 0] = o0 - l;
    out[node * 2 + 1] = o1 - l;
  }
}

extern "C" void kernel_launch(void* const* d_in, const int* in_sizes, int n_in,
                              void* d_out, int out_size, void* d_ws, size_t ws_size,
                              hipStream_t stream) {
  const float* x    = (const float*)d_in[0];
  const float* ew   = (const float*)d_in[1];
  const float* Wih1 = (const float*)d_in[2];
  const float* Whh1 = (const float*)d_in[3];
  const float* bih1 = (const float*)d_in[4];
  const float* bhh1 = (const float*)d_in[5];
  const float* ln_g = (const float*)d_in[6];
  const float* ln_b = (const float*)d_in[7];
  const float* Wih2 = (const float*)d_in[8];
  const float* Whh2 = (const float*)d_in[9];
  const float* bih2 = (const float*)d_in[10];
  const float* bhh2 = (const float*)d_in[11];
  const float* Wg1  = (const float*)d_in[12];
  const float* bg1  = (const float*)d_in[13];
  const float* Wg2  = (const float*)d_in[14];
  const float* bg2  = (const float*)d_in[15];
  const float* Wfc  = (const float*)d_in[16];
  const float* bfc  = (const float*)d_in[17];
  const int* ei     = (const int*)d_in[18];
  float* out = (float*)d_out;
  const int E = in_sizes[1];   // 262144

  float* ws   = (float*)d_ws;
  float* h2o  = ws;                    // 262144
  float* hWa  = ws + 262144;           // 262144
  float* aggB = ws + 524288;           // 262144
  unsigned long long* pk = (unsigned long long*)(ws + 786432);  // 8192 ull
  float* dinv = ws + 802816;           // 8192
  int*   off  = (int*)(ws + 811008);   // 8193
  int*   pos  = (int*)(ws + 819208);   // 8192
  int2*  ed   = (int2*)(ws + 827400);  // 262144 int2

  hipMemsetAsync((void*)pk, 0, 8192 * sizeof(unsigned long long), stream);
  hipLaunchKernelGGL(lstm_fused, dim3(NNODES / 16), dim3(512), 0, stream,
                     x, Wih1, Whh1, bih1, bhh1, ln_g, ln_b,
                     Wih2, Whh2, bih2, bhh2, Wg1, ei, ew, pk, E, h2o, hWa);
  hipLaunchKernelGGL(scan_k, dim3(1), dim3(1024), 0, stream, pk, off, pos, dinv);
  hipLaunchKernelGGL(scatter_k, dim3((E + 255) / 256), dim3(256), 0, stream, ei, ew, dinv, pos, ed, E);
  hipLaunchKernelGGL(gather_mid_k, dim3(NNODES / 16), dim3(512), 0, stream,
                     off, ed, dinv, hWa, bg1, Wg2, aggB);
  hipLaunchKernelGGL(gather_final_k, dim3(NNODES / 16), dim3(512), 0, stream,
                     off, ed, dinv, aggB, bg2, h2o, Wfc, bfc, out);
}